// Round 5
// baseline (2536.822 us; speedup 1.0000x reference)
//
#include <hip/hip_runtime.h>
#include <cstdint>
#include <utility>

#define NN0 80000
#define NE 1280000

static inline int cdiv(int a, int b){ return (a+b-1)/b; }

// plain matmul (used for final Fout=1 conv)
__global__ void k_matmul(const float* __restrict__ x, const float* __restrict__ W,
                         float* __restrict__ h, int n, int Fin, int Fout) {
  int t = blockIdx.x*blockDim.x + threadIdx.x;
  if (t >= n*Fout) return;
  int i = t / Fout, f = t - i*Fout;
  float s = 0.f;
  for (int k2 = 0; k2 < Fin; k2++) s += x[i*Fin+k2]*W[k2*Fout+f];
  h[t] = s;
}

// matmul (Fout=64) fused with BN-stats accumulation (stats[0:64]=sum, [64:128]=sumsq)
__global__ void k_matmul_bn(const float* __restrict__ x, const float* __restrict__ W,
                            float* __restrict__ h, float* __restrict__ stats,
                            int n, int Fin) {
  __shared__ float ls[64], lq[64];
  int t = blockIdx.x*blockDim.x + threadIdx.x;
  if (threadIdx.x < 64){ ls[threadIdx.x] = 0.f; lq[threadIdx.x] = 0.f; }
  __syncthreads();
  bool act = t < n*64;
  float s = 0.f;
  int f = t & 63;
  if (act){
    int i = t >> 6;
    for (int k2 = 0; k2 < Fin; k2++) s += x[i*Fin+k2]*W[k2*64+f];
    h[t] = s;
    atomicAdd(&ls[f], s); atomicAdd(&lq[f], s*s);
  }
  __syncthreads();
  if (threadIdx.x < 64){
    atomicAdd(&stats[threadIdx.x], ls[threadIdx.x]);
    atomicAdd(&stats[64+threadIdx.x], lq[threadIdx.x]);
  }
}

__global__ void k_zero_i(int* __restrict__ p, int n){
  int t = blockIdx.x*blockDim.x + threadIdx.x;
  if (t < n) p[t] = 0;
}

// ---- parallel exclusive scan: part (raw block sums) + fused final ----
__global__ void k_scan_part(const int* __restrict__ in, int* __restrict__ bsum, int n){
  __shared__ int ws[256];
  int base = blockIdx.x*1024 + threadIdx.x*4;
  int s = 0;
  #pragma unroll
  for (int u = 0; u < 4; u++){ int i = base+u; if (i < n) s += in[i]; }
  ws[threadIdx.x] = s; __syncthreads();
  for (int st = 128; st > 0; st >>= 1){
    if (threadIdx.x < st) ws[threadIdx.x] += ws[threadIdx.x+st];
    __syncthreads();
  }
  if (threadIdx.x == 0) bsum[blockIdx.x] = ws[0];
}

__device__ __forceinline__ int scan_block_off(const int* bsum, int nb, int* bws){
  int t = threadIdx.x;
  bws[t] = (t < nb) ? bsum[t] : 0; __syncthreads();
  for (int st = 1; st < 256; st <<= 1){
    int a = (t >= st) ? bws[t-st] : 0; __syncthreads();
    bws[t] += a; __syncthreads();
  }
  return (blockIdx.x == 0) ? 0 : bws[blockIdx.x-1];
}

// final stage for CSR: writes rp[0..n], cursor[0..n)
__global__ void k_scan_fin_rp(const int* __restrict__ in, const int* __restrict__ bsum, int nb,
                              int* __restrict__ rp, int* __restrict__ cursor, int n){
  __shared__ int bws[256]; __shared__ int ws[256];
  int blockoff = scan_block_off(bsum, nb, bws);
  int t = threadIdx.x;
  int base = blockIdx.x*1024 + t*4;
  int v[4]; int s = 0;
  #pragma unroll
  for (int u = 0; u < 4; u++){ int i = base+u; v[u] = (i < n) ? in[i] : 0; s += v[u]; }
  ws[t] = s; __syncthreads();
  for (int st = 1; st < 256; st <<= 1){
    int a = (t >= st) ? ws[t-st] : 0; __syncthreads();
    ws[t] += a; __syncthreads();
  }
  int off = blockoff + ws[t] - s;
  #pragma unroll
  for (int u = 0; u < 4; u++){
    int i = base+u;
    if (i < n){
      rp[i] = off; cursor[i] = off; off += v[u];
      if (i == n-1) rp[n] = off;
    }
  }
}

// final stage, in-place flat scan (radix histogram)
__global__ void k_scan_fin_flat(int* __restrict__ data, const int* __restrict__ bsum, int nb, int n){
  __shared__ int bws[256]; __shared__ int ws[256];
  int blockoff = scan_block_off(bsum, nb, bws);
  int t = threadIdx.x;
  int base = blockIdx.x*1024 + t*4;
  int v[4]; int s = 0;
  #pragma unroll
  for (int u = 0; u < 4; u++){ int i = base+u; v[u] = (i < n) ? data[i] : 0; s += v[u]; }
  ws[t] = s; __syncthreads();
  for (int st = 1; st < 256; st <<= 1){
    int a = (t >= st) ? ws[t-st] : 0; __syncthreads();
    ws[t] += a; __syncthreads();
  }
  int off = blockoff + ws[t] - s;
  #pragma unroll
  for (int u = 0; u < 4; u++){
    int i = base+u;
    if (i < n){ data[i] = off; off += v[u]; }
  }
}

// ---- CSR build, level 0 ----
__global__ void k_hist_full(const int* __restrict__ dst, int* __restrict__ indeg, int ne){
  int e = blockIdx.x*blockDim.x + threadIdx.x;
  if (e < ne) atomicAdd(&indeg[dst[e]], 1);
}
__global__ void k_scatter_full(const int* __restrict__ src, const int* __restrict__ dst,
                               int* __restrict__ cursor, int* __restrict__ col, int ne){
  int e = blockIdx.x*blockDim.x + threadIdx.x;
  if (e >= ne) return;
  int pos = atomicAdd(&cursor[dst[e]], 1);
  col[pos] = src[e];
}

// ---- CSR build for pooled level from parent CSR + injective mapping ----
__global__ void k_hist_mapped(const int* __restrict__ rp_p, const int* __restrict__ col_p,
                              const int* __restrict__ mapv, int* __restrict__ indeg, int np){
  int d = blockIdx.x*blockDim.x + threadIdx.x;
  if (d >= np) return;
  int md = mapv[d];
  if (md < 0) return;
  int c = 0, e = rp_p[d+1];
  for (int j = rp_p[d]; j < e; j++) if (mapv[col_p[j]] >= 0) c++;
  indeg[md] = c;
}
__global__ void k_scatter_mapped(const int* __restrict__ rp_p, const int* __restrict__ col_p,
                                 const int* __restrict__ mapv, const int* __restrict__ rp_c,
                                 int* __restrict__ col_c, int np){
  int d = blockIdx.x*blockDim.x + threadIdx.x;
  if (d >= np) return;
  int md = mapv[d];
  if (md < 0) return;
  int pos = rp_c[md], e = rp_p[d+1];
  for (int j = rp_p[d]; j < e; j++){
    int ms = mapv[col_p[j]];
    if (ms >= 0) col_c[pos++] = ms;
  }
}

// dinv[i] = rsqrt(indegree + fill); also zeroes BN stats for the upcoming conv
__global__ void k_dinv_rp(const int* __restrict__ rp, float* __restrict__ dinv,
                          float fill, int n, float* __restrict__ stats){
  int i = blockIdx.x*blockDim.x + threadIdx.x;
  if (stats && i < 128) stats[i] = 0.f;
  if (i < n) dinv[i] = 1.0f/sqrtf((float)(rp[i+1]-rp[i]) + fill);
}

// aggregate conv INPUT (x-space, linearity of GCN): 64-wide, one wave per node
__global__ void k_gather64(const int* __restrict__ rp, const int* __restrict__ col,
                           const float* __restrict__ dinv, const float* __restrict__ x,
                           float* __restrict__ y, float fill, int n){
  int t = blockIdx.x*blockDim.x + threadIdx.x;
  int i = t >> 6, f = t & 63;
  if (i >= n) return;
  int beg = rp[i], end = rp[i+1];
  float di = dinv[i];
  float acc = 0.f;
  for (int j = beg; j < end; j++){
    int s = col[j];
    acc += dinv[s]*x[s*64+f];
  }
  y[i*64+f] = di*acc + fill*di*di*x[i*64+f];
}

// 3-wide variant for the first conv (x_in has C_IN=3)
__global__ void k_gather3(const int* __restrict__ rp, const int* __restrict__ col,
                          const float* __restrict__ dinv, const float* __restrict__ x,
                          float* __restrict__ y, float fill, int n){
  int i = blockIdx.x*blockDim.x + threadIdx.x;
  if (i >= n) return;
  int beg = rp[i], end = rp[i+1];
  float di = dinv[i];
  float a0 = 0.f, a1 = 0.f, a2 = 0.f;
  for (int j = beg; j < end; j++){
    int s = col[j];
    float ds = dinv[s];
    a0 += ds*x[s*3+0]; a1 += ds*x[s*3+1]; a2 += ds*x[s*3+2];
  }
  float sl = fill*di*di;
  y[i*3+0] = di*a0 + sl*x[i*3+0];
  y[i*3+1] = di*a1 + sl*x[i*3+1];
  y[i*3+2] = di*a2 + sl*x[i*3+2];
}

// final conv (Fout=1, fill=1) fused with sigmoid; 1 thread per node
__global__ void k_gather_sig(const int* __restrict__ rp, const int* __restrict__ col,
                             const float* __restrict__ dinv, const float* __restrict__ h1,
                             float* __restrict__ out, int n){
  int i = blockIdx.x*blockDim.x + threadIdx.x;
  if (i >= n) return;
  int beg = rp[i], end = rp[i+1];
  float di = dinv[i];
  float acc = 0.f;
  for (int j = beg; j < end; j++) acc += dinv[col[j]]*h1[col[j]];
  float v = di*acc + di*di*h1[i];
  out[i] = 1.f/(1.f+expf(-v));
}

__global__ void k_bnrelu(float* __restrict__ x, const float* __restrict__ stats,
                         const float* __restrict__ gamma, const float* __restrict__ beta,
                         int n) {
  int t = blockIdx.x*blockDim.x + threadIdx.x;
  if (t >= n*64) return;
  int f = t & 63;
  float inv_n = 1.0f/(float)n;
  float mu = stats[f]*inv_n;
  float var = stats[64+f]*inv_n - mu*mu;
  float v = gamma[f]*(x[t]-mu)*(1.0f/sqrtf(var+1e-5f)) + beta[f];
  x[t] = fmaxf(v, 0.f);
}

// score + radix init fused
__global__ void k_score_init(const float* __restrict__ x, const float* __restrict__ pw,
                             float* __restrict__ score, unsigned* __restrict__ key,
                             int* __restrict__ idx, int n, int P) {
  int i = blockIdx.x*blockDim.x + threadIdx.x;
  if (i >= P) return;
  if (i < n){
    float s = 0.f, q = 0.f;
    for (int k2 = 0; k2 < 64; k2++){ float w = pw[k2]; s += x[i*64+k2]*w; q += w*w; }
    float sc = fmaxf(s/sqrtf(q), 0.f);
    score[i] = sc; key[i] = ~__float_as_uint(sc); idx[i] = i;
  } else { key[i] = 0xFFFFFFFFu; idx[i] = 0; }
}

__global__ void k_radix_hist(const unsigned* __restrict__ key, int* __restrict__ hist,
                             int shift, int nblk){
  __shared__ int lh[256];
  lh[threadIdx.x] = 0; __syncthreads();
  unsigned d = (key[blockIdx.x*256 + threadIdx.x] >> shift) & 255u;
  atomicAdd(&lh[d], 1);
  __syncthreads();
  hist[threadIdx.x*nblk + blockIdx.x] = lh[threadIdx.x];
}

// ballot-based stable scatter (wave64): rank within wave via bit ballots,
// cross-wave offsets via per-wave per-digit LDS counts.
__global__ void k_radix_scatter(const unsigned* __restrict__ keyin, const int* __restrict__ idxin,
                                unsigned* __restrict__ keyout, int* __restrict__ idxout,
                                const int* __restrict__ hist, int shift, int nblk){
  __shared__ int wcnt[4][256];
  int t = threadIdx.x, lane = t & 63, w = t >> 6;
  #pragma unroll
  for (int u = 0; u < 4; u++) wcnt[u][t] = 0;
  __syncthreads();
  int g = blockIdx.x*256 + t;
  unsigned kk = keyin[g];
  int id = idxin[g];
  unsigned d = (kk >> shift) & 255u;
  unsigned long long m = ~0ull;
  #pragma unroll
  for (int b = 0; b < 8; b++){
    unsigned long long bal = __ballot((d >> b) & 1u);
    m &= ((d >> b) & 1u) ? bal : ~bal;
  }
  int rnk = __popcll(m & ((1ull << lane) - 1ull));
  if (rnk == 0) wcnt[w][d] = __popcll(m);
  __syncthreads();
  int off2 = 0;
  for (int w2 = 0; w2 < w; w2++) off2 += wcnt[w2][d];
  int pos = hist[d*nblk + blockIdx.x] + off2 + rnk;
  keyout[pos] = kk; idxout[pos] = id;
}

__global__ void k_select_sorted(const int* __restrict__ idxs, int* __restrict__ perm,
                                int* __restrict__ mapping, int n, int k){
  int r = blockIdx.x*blockDim.x + threadIdx.x;
  if (r >= n) return;
  int i = idxs[r];
  mapping[i] = (r < k) ? r : -1;
  if (r < k) perm[r] = i;
}

__global__ void k_gather_scale(const float* __restrict__ x, const float* __restrict__ score,
                               const int* __restrict__ perm, float* __restrict__ xk, int k) {
  int t = blockIdx.x*blockDim.x + threadIdx.x;
  if (t >= k*64) return;
  int r = t >> 6, f = t & 63;
  int i = perm[r];
  xk[t] = x[i*64+f]*score[i];
}

__global__ void k_scatter_add(const float* __restrict__ xup, const int* __restrict__ perm,
                              float* __restrict__ res, int k) {
  int t = blockIdx.x*blockDim.x + threadIdx.x;
  if (t >= k*64) return;
  int r = t >> 6, f = t & 63;
  res[perm[r]*64+f] += xup[t];
}

extern "C" void kernel_launch(void* const* d_in, const int* in_sizes, int n_in,
                              void* d_out, int out_size, void* d_ws, size_t ws_size,
                              hipStream_t stream) {
  const float* x_in = (const float*)d_in[0];
  const int* ei = (const int*)d_in[1];
  const int* src0 = ei;
  const int* dst0 = ei + NE;
  const float* W_d[4] = {(const float*)d_in[2],(const float*)d_in[5],(const float*)d_in[8],(const float*)d_in[11]};
  const float* g_d[4] = {(const float*)d_in[3],(const float*)d_in[6],(const float*)d_in[9],(const float*)d_in[12]};
  const float* b_d[4] = {(const float*)d_in[4],(const float*)d_in[7],(const float*)d_in[10],(const float*)d_in[13]};
  const float* pw[3]  = {(const float*)d_in[14],(const float*)d_in[15],(const float*)d_in[16]};
  const float* W_u[2] = {(const float*)d_in[17],(const float*)d_in[20]};
  const float* g_u[2] = {(const float*)d_in[18],(const float*)d_in[21]};
  const float* b_u[2] = {(const float*)d_in[19],(const float*)d_in[22]};
  const float* W_out  = (const float*)d_in[23];
  float* out = (float*)d_out;

  float* base = (float*)d_ws;
  size_t off = 0;
  auto alloc = [&](size_t nf){ float* p = base + off; off += nf; return p; };
  float* x0 = alloc(5120000);
  float* x1 = alloc(2560000);
  float* x2 = alloc(1280000);
  float* x3 = alloc(640000);
  float* A  = alloc(2560000);
  float* h  = alloc(5120000);
  int* col0 = (int*)alloc(NE);
  int* col1 = (int*)alloc(NE);
  int* col2 = (int*)alloc(NE);
  int* col3 = (int*)alloc(NE);
  int* rp0 = (int*)alloc(80001);
  int* rp1 = (int*)alloc(40001);
  int* rp2 = (int*)alloc(20001);
  int* rp3 = (int*)alloc(10001);
  int* indeg  = (int*)alloc(NN0);
  int* cursor = (int*)alloc(NN0);
  float* dinv  = alloc(NN0);
  float* score = alloc(NN0);
  int* mapv = (int*)alloc(NN0);
  int* p0 = (int*)alloc(40000);
  int* p1 = (int*)alloc(20000);
  int* p2 = (int*)alloc(10000);
  float* stats = alloc(128);
  unsigned* keyA = (unsigned*)alloc(80128);
  unsigned* keyB = (unsigned*)alloc(80128);
  int* idxA = (int*)alloc(80128);
  int* idxB = (int*)alloc(80128);
  int* hist = (int*)alloc(80128);
  int* bsum = (int*)alloc(256);
  (void)ws_size; (void)in_sizes; (void)n_in; (void)out_size;

  const int B = 256;

  auto scan_csr = [&](const int* indeg_, int* rp, int* cur, int n2){
    int nb = cdiv(n2, 1024);
    k_scan_part  <<<nb, 256, 0, stream>>>(indeg_, bsum, n2);
    k_scan_fin_rp<<<nb, 256, 0, stream>>>(indeg_, bsum, nb, rp, cur, n2);
  };
  auto scan_flat = [&](int* data, int n2){
    int nb = cdiv(n2, 1024);
    k_scan_part    <<<nb, 256, 0, stream>>>(data, bsum, n2);
    k_scan_fin_flat<<<nb, 256, 0, stream>>>(data, bsum, nb, n2);
  };

  // agg-first conv: y = dinv*agg(dinv_s x_s) + fill*dinv^2*x  ; out = BN(y @ W)
  auto conv = [&](const float* xin, const float* W, int Fin, int n, float fill,
                  const int* rp, const int* col, float* dstb){
    k_dinv_rp<<<cdiv(n,B), B, 0, stream>>>(rp, dinv, fill, n, stats);
    if (Fin == 3) k_gather3 <<<cdiv(n,B),    B, 0, stream>>>(rp, col, dinv, xin, h, fill, n);
    else          k_gather64<<<cdiv(n*64,B), B, 0, stream>>>(rp, col, dinv, xin, h, fill, n);
    k_matmul_bn<<<cdiv(n*64,B), B, 0, stream>>>(h, W, dstb, stats, n, Fin);
  };

  auto bn_relu = [&](float* xb, const float* g, const float* bt, int n) {
    k_bnrelu<<<cdiv(n*64,B), B, 0, stream>>>(xb, stats, g, bt, n);
  };

  auto pool = [&](const float* xb, const float* w, int n, int k, int* pm, float* xk) {
    int nblk = cdiv(n, 256), P = nblk*256;
    k_score_init<<<cdiv(P,B), B, 0, stream>>>(xb, w, score, keyA, idxA, n, P);
    unsigned* ka = keyA; int* ia = idxA; unsigned* kb = keyB; int* ib = idxB;
    for (int pass = 0; pass < 4; pass++) {
      k_radix_hist<<<nblk, 256, 0, stream>>>(ka, hist, pass*8, nblk);
      scan_flat(hist, nblk*256);
      k_radix_scatter<<<nblk, 256, 0, stream>>>(ka, ia, kb, ib, hist, pass*8, nblk);
      std::swap(ka, kb); std::swap(ia, ib);
    }
    k_select_sorted<<<cdiv(n,B), B, 0, stream>>>(ia, pm, mapv, n, k);
    k_gather_scale <<<cdiv(k*64,B), B, 0, stream>>>(xb, score, pm, xk, k);
  };

  auto csr_mapped = [&](const int* rp_p, const int* col_p, int np, int nc,
                        int* rp_c, int* col_c){
    k_hist_mapped<<<cdiv(np,B), B, 0, stream>>>(rp_p, col_p, mapv, indeg, np);
    scan_csr(indeg, rp_c, cursor, nc);
    k_scatter_mapped<<<cdiv(np,B), B, 0, stream>>>(rp_p, col_p, mapv, rp_c, col_c, np);
  };

  // ---- CSR for level 0 ----
  k_zero_i   <<<cdiv(NN0,B), B, 0, stream>>>(indeg, NN0);
  k_hist_full<<<cdiv(NE,B),  B, 0, stream>>>(dst0, indeg, NE);
  scan_csr(indeg, rp0, cursor, NN0);
  k_scatter_full<<<cdiv(NE,B), B, 0, stream>>>(src0, dst0, cursor, col0, NE);

  // ---- down path ----
  conv(x_in, W_d[0], 3, NN0, 2.f, rp0, col0, x0);
  bn_relu(x0, g_d[0], b_d[0], NN0);

  pool(x0, pw[0], NN0, 40000, p0, A);
  csr_mapped(rp0, col0, NN0, 40000, rp1, col1);
  conv(A, W_d[1], 64, 40000, 2.f, rp1, col1, x1);
  bn_relu(x1, g_d[1], b_d[1], 40000);

  pool(x1, pw[1], 40000, 20000, p1, A);
  csr_mapped(rp1, col1, 40000, 20000, rp2, col2);
  conv(A, W_d[2], 64, 20000, 2.f, rp2, col2, x2);
  bn_relu(x2, g_d[2], b_d[2], 20000);

  pool(x2, pw[2], 20000, 10000, p2, A);
  csr_mapped(rp2, col2, 20000, 10000, rp3, col3);
  conv(A, W_d[3], 64, 10000, 2.f, rp3, col3, x3);
  bn_relu(x3, g_d[3], b_d[3], 10000);

  // ---- up path ----
  k_scatter_add<<<cdiv(10000*64,B), B, 0, stream>>>(x3, p2, x2, 10000);
  conv(x2, W_u[0], 64, 20000, 2.f, rp2, col2, A);
  bn_relu(A, g_u[0], b_u[0], 20000);

  k_scatter_add<<<cdiv(20000*64,B), B, 0, stream>>>(A, p1, x1, 20000);
  conv(x1, W_u[1], 64, 40000, 2.f, rp1, col1, A);
  bn_relu(A, g_u[1], b_u[1], 40000);

  k_scatter_add<<<cdiv(40000*64,B), B, 0, stream>>>(A, p0, x0, 40000);

  // ---- final conv (fill = 1.0) fused with sigmoid ----
  float* h1 = score;  // reuse
  k_matmul <<<cdiv(NN0,B), B, 0, stream>>>(x0, W_out, h1, NN0, 64, 1);
  k_dinv_rp<<<cdiv(NN0,B), B, 0, stream>>>(rp0, dinv, 1.f, NN0, (float*)nullptr);
  k_gather_sig<<<cdiv(NN0,B), B, 0, stream>>>(rp0, col0, dinv, h1, out, NN0);
}

// Round 6
// 1151.374 us; speedup vs baseline: 2.2033x; 2.2033x over previous
//
#include <hip/hip_runtime.h>
#include <cstdint>
#include <utility>

#define NN0 80000
#define NE 1280000

static inline int cdiv(int a, int b){ return (a+b-1)/b; }

// plain matmul (used for final Fout=1 conv)
__global__ void k_matmul(const float* __restrict__ x, const float* __restrict__ W,
                         float* __restrict__ h, int n, int Fin, int Fout) {
  int t = blockIdx.x*blockDim.x + threadIdx.x;
  if (t >= n*Fout) return;
  int i = t / Fout, f = t - i*Fout;
  float s = 0.f;
  for (int k2 = 0; k2 < Fin; k2++) s += x[i*Fin+k2]*W[k2*Fout+f];
  h[t] = s;
}

// matmul (Fout=64) fused with BN-stats. Grid-stride with CAPPED grid so the
// global-atomic fan-in to stats[] is O(gridDim*128), not O(n). Per-thread
// register accumulators: f = t&63 is loop-invariant (stride % 64 == 0).
__global__ void k_matmul_bn(const float* __restrict__ x, const float* __restrict__ W,
                            float* __restrict__ h, float* __restrict__ stats,
                            int n, int Fin) {
  __shared__ float ls[64], lq[64];
  int f = threadIdx.x & 63;
  float sa = 0.f, sq = 0.f;
  int total = n*64, stride = gridDim.x*blockDim.x;
  for (int t = blockIdx.x*blockDim.x + threadIdx.x; t < total; t += stride){
    int i = t >> 6;
    float s = 0.f;
    for (int k2 = 0; k2 < Fin; k2++) s += x[i*Fin+k2]*W[k2*64+f];
    h[t] = s; sa += s; sq += s*s;
  }
  if (threadIdx.x < 64){ ls[threadIdx.x] = 0.f; lq[threadIdx.x] = 0.f; }
  __syncthreads();
  atomicAdd(&ls[f], sa); atomicAdd(&lq[f], sq);
  __syncthreads();
  if (threadIdx.x < 64){
    atomicAdd(&stats[threadIdx.x], ls[threadIdx.x]);
    atomicAdd(&stats[64+threadIdx.x], lq[threadIdx.x]);
  }
}

__global__ void k_zero_i(int* __restrict__ p, int n){
  int t = blockIdx.x*blockDim.x + threadIdx.x;
  if (t < n) p[t] = 0;
}

// ---- parallel exclusive scan: part (raw block sums) + fused final ----
__global__ void k_scan_part(const int* __restrict__ in, int* __restrict__ bsum, int n){
  __shared__ int ws[256];
  int base = blockIdx.x*1024 + threadIdx.x*4;
  int s = 0;
  #pragma unroll
  for (int u = 0; u < 4; u++){ int i = base+u; if (i < n) s += in[i]; }
  ws[threadIdx.x] = s; __syncthreads();
  for (int st = 128; st > 0; st >>= 1){
    if (threadIdx.x < st) ws[threadIdx.x] += ws[threadIdx.x+st];
    __syncthreads();
  }
  if (threadIdx.x == 0) bsum[blockIdx.x] = ws[0];
}

__device__ __forceinline__ int scan_block_off(const int* bsum, int nb, int* bws){
  int t = threadIdx.x;
  bws[t] = (t < nb) ? bsum[t] : 0; __syncthreads();
  for (int st = 1; st < 256; st <<= 1){
    int a = (t >= st) ? bws[t-st] : 0; __syncthreads();
    bws[t] += a; __syncthreads();
  }
  return (blockIdx.x == 0) ? 0 : bws[blockIdx.x-1];
}

// final stage for CSR: writes rp[0..n], cursor[0..n)
__global__ void k_scan_fin_rp(const int* __restrict__ in, const int* __restrict__ bsum, int nb,
                              int* __restrict__ rp, int* __restrict__ cursor, int n){
  __shared__ int bws[256]; __shared__ int ws[256];
  int blockoff = scan_block_off(bsum, nb, bws);
  int t = threadIdx.x;
  int base = blockIdx.x*1024 + t*4;
  int v[4]; int s = 0;
  #pragma unroll
  for (int u = 0; u < 4; u++){ int i = base+u; v[u] = (i < n) ? in[i] : 0; s += v[u]; }
  ws[t] = s; __syncthreads();
  for (int st = 1; st < 256; st <<= 1){
    int a = (t >= st) ? ws[t-st] : 0; __syncthreads();
    ws[t] += a; __syncthreads();
  }
  int off = blockoff + ws[t] - s;
  #pragma unroll
  for (int u = 0; u < 4; u++){
    int i = base+u;
    if (i < n){
      rp[i] = off; cursor[i] = off; off += v[u];
      if (i == n-1) rp[n] = off;
    }
  }
}

// final stage, in-place flat scan (radix histogram)
__global__ void k_scan_fin_flat(int* __restrict__ data, const int* __restrict__ bsum, int nb, int n){
  __shared__ int bws[256]; __shared__ int ws[256];
  int blockoff = scan_block_off(bsum, nb, bws);
  int t = threadIdx.x;
  int base = blockIdx.x*1024 + t*4;
  int v[4]; int s = 0;
  #pragma unroll
  for (int u = 0; u < 4; u++){ int i = base+u; v[u] = (i < n) ? data[i] : 0; s += v[u]; }
  ws[t] = s; __syncthreads();
  for (int st = 1; st < 256; st <<= 1){
    int a = (t >= st) ? ws[t-st] : 0; __syncthreads();
    ws[t] += a; __syncthreads();
  }
  int off = blockoff + ws[t] - s;
  #pragma unroll
  for (int u = 0; u < 4; u++){
    int i = base+u;
    if (i < n){ data[i] = off; off += v[u]; }
  }
}

// ---- CSR build, level 0 ----
__global__ void k_hist_full(const int* __restrict__ dst, int* __restrict__ indeg, int ne){
  int e = blockIdx.x*blockDim.x + threadIdx.x;
  if (e < ne) atomicAdd(&indeg[dst[e]], 1);
}
__global__ void k_scatter_full(const int* __restrict__ src, const int* __restrict__ dst,
                               int* __restrict__ cursor, int* __restrict__ col, int ne){
  int e = blockIdx.x*blockDim.x + threadIdx.x;
  if (e >= ne) return;
  int pos = atomicAdd(&cursor[dst[e]], 1);
  col[pos] = src[e];
}

// ---- CSR build for pooled level from parent CSR + injective mapping ----
__global__ void k_hist_mapped(const int* __restrict__ rp_p, const int* __restrict__ col_p,
                              const int* __restrict__ mapv, int* __restrict__ indeg, int np){
  int d = blockIdx.x*blockDim.x + threadIdx.x;
  if (d >= np) return;
  int md = mapv[d];
  if (md < 0) return;
  int c = 0, e = rp_p[d+1];
  for (int j = rp_p[d]; j < e; j++) if (mapv[col_p[j]] >= 0) c++;
  indeg[md] = c;
}
__global__ void k_scatter_mapped(const int* __restrict__ rp_p, const int* __restrict__ col_p,
                                 const int* __restrict__ mapv, const int* __restrict__ rp_c,
                                 int* __restrict__ col_c, int np){
  int d = blockIdx.x*blockDim.x + threadIdx.x;
  if (d >= np) return;
  int md = mapv[d];
  if (md < 0) return;
  int pos = rp_c[md], e = rp_p[d+1];
  for (int j = rp_p[d]; j < e; j++){
    int ms = mapv[col_p[j]];
    if (ms >= 0) col_c[pos++] = ms;
  }
}

// dinv[i] = rsqrt(indegree + fill); also zeroes BN stats for the upcoming conv
__global__ void k_dinv_rp(const int* __restrict__ rp, float* __restrict__ dinv,
                          float fill, int n, float* __restrict__ stats){
  int i = blockIdx.x*blockDim.x + threadIdx.x;
  if (stats && i < 128) stats[i] = 0.f;
  if (i < n) dinv[i] = 1.0f/sqrtf((float)(rp[i+1]-rp[i]) + fill);
}

// aggregate conv INPUT (x-space, linearity of GCN): 64-wide, one wave per node
__global__ void k_gather64(const int* __restrict__ rp, const int* __restrict__ col,
                           const float* __restrict__ dinv, const float* __restrict__ x,
                           float* __restrict__ y, float fill, int n){
  int t = blockIdx.x*blockDim.x + threadIdx.x;
  int i = t >> 6, f = t & 63;
  if (i >= n) return;
  int beg = rp[i], end = rp[i+1];
  float di = dinv[i];
  float acc = 0.f;
  for (int j = beg; j < end; j++){
    int s = col[j];
    acc += dinv[s]*x[s*64+f];
  }
  y[i*64+f] = di*acc + fill*di*di*x[i*64+f];
}

// 3-wide variant for the first conv (x_in has C_IN=3)
__global__ void k_gather3(const int* __restrict__ rp, const int* __restrict__ col,
                          const float* __restrict__ dinv, const float* __restrict__ x,
                          float* __restrict__ y, float fill, int n){
  int i = blockIdx.x*blockDim.x + threadIdx.x;
  if (i >= n) return;
  int beg = rp[i], end = rp[i+1];
  float di = dinv[i];
  float a0 = 0.f, a1 = 0.f, a2 = 0.f;
  for (int j = beg; j < end; j++){
    int s = col[j];
    float ds = dinv[s];
    a0 += ds*x[s*3+0]; a1 += ds*x[s*3+1]; a2 += ds*x[s*3+2];
  }
  float sl = fill*di*di;
  y[i*3+0] = di*a0 + sl*x[i*3+0];
  y[i*3+1] = di*a1 + sl*x[i*3+1];
  y[i*3+2] = di*a2 + sl*x[i*3+2];
}

// final conv (Fout=1, fill=1) fused with sigmoid; 1 thread per node
__global__ void k_gather_sig(const int* __restrict__ rp, const int* __restrict__ col,
                             const float* __restrict__ dinv, const float* __restrict__ h1,
                             float* __restrict__ out, int n){
  int i = blockIdx.x*blockDim.x + threadIdx.x;
  if (i >= n) return;
  int beg = rp[i], end = rp[i+1];
  float di = dinv[i];
  float acc = 0.f;
  for (int j = beg; j < end; j++) acc += dinv[col[j]]*h1[col[j]];
  float v = di*acc + di*di*h1[i];
  out[i] = 1.f/(1.f+expf(-v));
}

__global__ void k_bnrelu(float* __restrict__ x, const float* __restrict__ stats,
                         const float* __restrict__ gamma, const float* __restrict__ beta,
                         int n) {
  int t = blockIdx.x*blockDim.x + threadIdx.x;
  if (t >= n*64) return;
  int f = t & 63;
  float inv_n = 1.0f/(float)n;
  float mu = stats[f]*inv_n;
  float var = stats[64+f]*inv_n - mu*mu;
  float v = gamma[f]*(x[t]-mu)*(1.0f/sqrtf(var+1e-5f)) + beta[f];
  x[t] = fmaxf(v, 0.f);
}

// score + radix init fused
__global__ void k_score_init(const float* __restrict__ x, const float* __restrict__ pw,
                             float* __restrict__ score, unsigned* __restrict__ key,
                             int* __restrict__ idx, int n, int P) {
  int i = blockIdx.x*blockDim.x + threadIdx.x;
  if (i >= P) return;
  if (i < n){
    float s = 0.f, q = 0.f;
    for (int k2 = 0; k2 < 64; k2++){ float w = pw[k2]; s += x[i*64+k2]*w; q += w*w; }
    float sc = fmaxf(s/sqrtf(q), 0.f);
    score[i] = sc; key[i] = ~__float_as_uint(sc); idx[i] = i;
  } else { key[i] = 0xFFFFFFFFu; idx[i] = 0; }
}

__global__ void k_radix_hist(const unsigned* __restrict__ key, int* __restrict__ hist,
                             int shift, int nblk){
  __shared__ int lh[256];
  lh[threadIdx.x] = 0; __syncthreads();
  unsigned d = (key[blockIdx.x*256 + threadIdx.x] >> shift) & 255u;
  atomicAdd(&lh[d], 1);
  __syncthreads();
  hist[threadIdx.x*nblk + blockIdx.x] = lh[threadIdx.x];
}

// ballot-based stable scatter (wave64): rank within wave via bit ballots,
// cross-wave offsets via per-wave per-digit LDS counts.
__global__ void k_radix_scatter(const unsigned* __restrict__ keyin, const int* __restrict__ idxin,
                                unsigned* __restrict__ keyout, int* __restrict__ idxout,
                                const int* __restrict__ hist, int shift, int nblk){
  __shared__ int wcnt[4][256];
  int t = threadIdx.x, lane = t & 63, w = t >> 6;
  #pragma unroll
  for (int u = 0; u < 4; u++) wcnt[u][t] = 0;
  __syncthreads();
  int g = blockIdx.x*256 + t;
  unsigned kk = keyin[g];
  int id = idxin[g];
  unsigned d = (kk >> shift) & 255u;
  unsigned long long m = ~0ull;
  #pragma unroll
  for (int b = 0; b < 8; b++){
    unsigned long long bal = __ballot((d >> b) & 1u);
    m &= ((d >> b) & 1u) ? bal : ~bal;
  }
  int rnk = __popcll(m & ((1ull << lane) - 1ull));
  if (rnk == 0) wcnt[w][d] = __popcll(m);
  __syncthreads();
  int off2 = 0;
  for (int w2 = 0; w2 < w; w2++) off2 += wcnt[w2][d];
  int pos = hist[d*nblk + blockIdx.x] + off2 + rnk;
  keyout[pos] = kk; idxout[pos] = id;
}

__global__ void k_select_sorted(const int* __restrict__ idxs, int* __restrict__ perm,
                                int* __restrict__ mapping, int n, int k){
  int r = blockIdx.x*blockDim.x + threadIdx.x;
  if (r >= n) return;
  int i = idxs[r];
  mapping[i] = (r < k) ? r : -1;
  if (r < k) perm[r] = i;
}

__global__ void k_gather_scale(const float* __restrict__ x, const float* __restrict__ score,
                               const int* __restrict__ perm, float* __restrict__ xk, int k) {
  int t = blockIdx.x*blockDim.x + threadIdx.x;
  if (t >= k*64) return;
  int r = t >> 6, f = t & 63;
  int i = perm[r];
  xk[t] = x[i*64+f]*score[i];
}

__global__ void k_scatter_add(const float* __restrict__ xup, const int* __restrict__ perm,
                              float* __restrict__ res, int k) {
  int t = blockIdx.x*blockDim.x + threadIdx.x;
  if (t >= k*64) return;
  int r = t >> 6, f = t & 63;
  res[perm[r]*64+f] += xup[t];
}

extern "C" void kernel_launch(void* const* d_in, const int* in_sizes, int n_in,
                              void* d_out, int out_size, void* d_ws, size_t ws_size,
                              hipStream_t stream) {
  const float* x_in = (const float*)d_in[0];
  const int* ei = (const int*)d_in[1];
  const int* src0 = ei;
  const int* dst0 = ei + NE;
  const float* W_d[4] = {(const float*)d_in[2],(const float*)d_in[5],(const float*)d_in[8],(const float*)d_in[11]};
  const float* g_d[4] = {(const float*)d_in[3],(const float*)d_in[6],(const float*)d_in[9],(const float*)d_in[12]};
  const float* b_d[4] = {(const float*)d_in[4],(const float*)d_in[7],(const float*)d_in[10],(const float*)d_in[13]};
  const float* pw[3]  = {(const float*)d_in[14],(const float*)d_in[15],(const float*)d_in[16]};
  const float* W_u[2] = {(const float*)d_in[17],(const float*)d_in[20]};
  const float* g_u[2] = {(const float*)d_in[18],(const float*)d_in[21]};
  const float* b_u[2] = {(const float*)d_in[19],(const float*)d_in[22]};
  const float* W_out  = (const float*)d_in[23];
  float* out = (float*)d_out;

  float* base = (float*)d_ws;
  size_t off = 0;
  auto alloc = [&](size_t nf){ float* p = base + off; off += nf; return p; };
  float* x0 = alloc(5120000);
  float* x1 = alloc(2560000);
  float* x2 = alloc(1280000);
  float* x3 = alloc(640000);
  float* A  = alloc(2560000);
  float* h  = alloc(5120000);
  int* col0 = (int*)alloc(NE);
  int* col1 = (int*)alloc(NE);
  int* col2 = (int*)alloc(NE);
  int* col3 = (int*)alloc(NE);
  int* rp0 = (int*)alloc(80001);
  int* rp1 = (int*)alloc(40001);
  int* rp2 = (int*)alloc(20001);
  int* rp3 = (int*)alloc(10001);
  int* indeg  = (int*)alloc(NN0);
  int* cursor = (int*)alloc(NN0);
  float* dinv  = alloc(NN0);
  float* score = alloc(NN0);
  int* mapv = (int*)alloc(NN0);
  int* p0 = (int*)alloc(40000);
  int* p1 = (int*)alloc(20000);
  int* p2 = (int*)alloc(10000);
  float* stats = alloc(128);
  unsigned* keyA = (unsigned*)alloc(80128);
  unsigned* keyB = (unsigned*)alloc(80128);
  int* idxA = (int*)alloc(80128);
  int* idxB = (int*)alloc(80128);
  int* hist = (int*)alloc(80128);
  int* bsum = (int*)alloc(256);
  (void)ws_size; (void)in_sizes; (void)n_in; (void)out_size;

  const int B = 256;

  auto scan_csr = [&](const int* indeg_, int* rp, int* cur, int n2){
    int nb = cdiv(n2, 1024);
    k_scan_part  <<<nb, 256, 0, stream>>>(indeg_, bsum, n2);
    k_scan_fin_rp<<<nb, 256, 0, stream>>>(indeg_, bsum, nb, rp, cur, n2);
  };
  auto scan_flat = [&](int* data, int n2){
    int nb = cdiv(n2, 1024);
    k_scan_part    <<<nb, 256, 0, stream>>>(data, bsum, n2);
    k_scan_fin_flat<<<nb, 256, 0, stream>>>(data, bsum, nb, n2);
  };

  // agg-first conv: y = dinv*agg(dinv_s x_s) + fill*dinv^2*x  ; out = BN(y @ W)
  auto conv = [&](const float* xin, const float* W, int Fin, int n, float fill,
                  const int* rp, const int* col, float* dstb){
    k_dinv_rp<<<cdiv(n,B), B, 0, stream>>>(rp, dinv, fill, n, stats);
    if (Fin == 3) k_gather3 <<<cdiv(n,B),    B, 0, stream>>>(rp, col, dinv, xin, h, fill, n);
    else          k_gather64<<<cdiv(n*64,B), B, 0, stream>>>(rp, col, dinv, xin, h, fill, n);
    int mb = cdiv(n*64, B); if (mb > 1024) mb = 1024;   // cap: bounds stats atomic fan-in
    k_matmul_bn<<<mb, B, 0, stream>>>(h, W, dstb, stats, n, Fin);
  };

  auto bn_relu = [&](float* xb, const float* g, const float* bt, int n) {
    k_bnrelu<<<cdiv(n*64,B), B, 0, stream>>>(xb, stats, g, bt, n);
  };

  auto pool = [&](const float* xb, const float* w, int n, int k, int* pm, float* xk) {
    int nblk = cdiv(n, 256), P = nblk*256;
    k_score_init<<<cdiv(P,B), B, 0, stream>>>(xb, w, score, keyA, idxA, n, P);
    unsigned* ka = keyA; int* ia = idxA; unsigned* kb = keyB; int* ib = idxB;
    for (int pass = 0; pass < 4; pass++) {
      k_radix_hist<<<nblk, 256, 0, stream>>>(ka, hist, pass*8, nblk);
      scan_flat(hist, nblk*256);
      k_radix_scatter<<<nblk, 256, 0, stream>>>(ka, ia, kb, ib, hist, pass*8, nblk);
      std::swap(ka, kb); std::swap(ia, ib);
    }
    k_select_sorted<<<cdiv(n,B), B, 0, stream>>>(ia, pm, mapv, n, k);
    k_gather_scale <<<cdiv(k*64,B), B, 0, stream>>>(xb, score, pm, xk, k);
  };

  auto csr_mapped = [&](const int* rp_p, const int* col_p, int np, int nc,
                        int* rp_c, int* col_c){
    k_hist_mapped<<<cdiv(np,B), B, 0, stream>>>(rp_p, col_p, mapv, indeg, np);
    scan_csr(indeg, rp_c, cursor, nc);
    k_scatter_mapped<<<cdiv(np,B), B, 0, stream>>>(rp_p, col_p, mapv, rp_c, col_c, np);
  };

  // ---- CSR for level 0 ----
  k_zero_i   <<<cdiv(NN0,B), B, 0, stream>>>(indeg, NN0);
  k_hist_full<<<cdiv(NE,B),  B, 0, stream>>>(dst0, indeg, NE);
  scan_csr(indeg, rp0, cursor, NN0);
  k_scatter_full<<<cdiv(NE,B), B, 0, stream>>>(src0, dst0, cursor, col0, NE);

  // ---- down path ----
  conv(x_in, W_d[0], 3, NN0, 2.f, rp0, col0, x0);
  bn_relu(x0, g_d[0], b_d[0], NN0);

  pool(x0, pw[0], NN0, 40000, p0, A);
  csr_mapped(rp0, col0, NN0, 40000, rp1, col1);
  conv(A, W_d[1], 64, 40000, 2.f, rp1, col1, x1);
  bn_relu(x1, g_d[1], b_d[1], 40000);

  pool(x1, pw[1], 40000, 20000, p1, A);
  csr_mapped(rp1, col1, 40000, 20000, rp2, col2);
  conv(A, W_d[2], 64, 20000, 2.f, rp2, col2, x2);
  bn_relu(x2, g_d[2], b_d[2], 20000);

  pool(x2, pw[2], 20000, 10000, p2, A);
  csr_mapped(rp2, col2, 20000, 10000, rp3, col3);
  conv(A, W_d[3], 64, 10000, 2.f, rp3, col3, x3);
  bn_relu(x3, g_d[3], b_d[3], 10000);

  // ---- up path ----
  k_scatter_add<<<cdiv(10000*64,B), B, 0, stream>>>(x3, p2, x2, 10000);
  conv(x2, W_u[0], 64, 20000, 2.f, rp2, col2, A);
  bn_relu(A, g_u[0], b_u[0], 20000);

  k_scatter_add<<<cdiv(20000*64,B), B, 0, stream>>>(A, p1, x1, 20000);
  conv(x1, W_u[1], 64, 40000, 2.f, rp1, col1, A);
  bn_relu(A, g_u[1], b_u[1], 40000);

  k_scatter_add<<<cdiv(40000*64,B), B, 0, stream>>>(A, p0, x0, 40000);

  // ---- final conv (fill = 1.0) fused with sigmoid ----
  float* h1 = score;  // reuse
  k_matmul <<<cdiv(NN0,B), B, 0, stream>>>(x0, W_out, h1, NN0, 64, 1);
  k_dinv_rp<<<cdiv(NN0,B), B, 0, stream>>>(rp0, dinv, 1.f, NN0, (float*)nullptr);
  k_gather_sig<<<cdiv(NN0,B), B, 0, stream>>>(rp0, col0, dinv, h1, out, NN0);
}